// Round 1
// baseline (122.949 us; speedup 1.0000x reference)
//
#include <hip/hip_runtime.h>

#define TT 262144
#define BB 16
#define SS 65536      // TT/4 quads per batch
#define WSTRIDE 132   // padded per-phase combined-filter length

// ---------------------------------------------------------------------------
// Kernel 0: build combined filter W[p][i] = C_p[126+p-i], i in [0,132)
//   C_p[dd] = 4 * sum_k sum_{j == 3-p mod 4} H[k][124-j-dd] * G[k][j]
//   out[4u+p] = sum_i W[p][i] * x[4u-64+i]   (valid i in [2+p, 126+p])
// ---------------------------------------------------------------------------
__global__ void build_w(const float* __restrict__ H, const float* __restrict__ G,
                        float* __restrict__ W) {
    int e = blockIdx.x * blockDim.x + threadIdx.x;
    if (e >= 4 * WSTRIDE) return;
    int p = e / WSTRIDE;
    int i = e % WSTRIDE;
    int dd = 126 + p - i;            // index into C_p, valid 0..124
    float acc = 0.f;
    if (dd >= 0 && dd <= 124) {
        int j0 = (3 - p) & 3;
        for (int k = 0; k < 4; ++k) {
            for (int j = j0; j <= 62; j += 4) {
                int a = 124 - j - dd;          // H tap index
                if (a >= 0 && a <= 62) acc += H[k * 63 + a] * G[k * 63 + j];
            }
        }
    }
    W[e] = 4.0f * acc;
}

// ---------------------------------------------------------------------------
// Kernel 1: fused PQMF. One thread = one quad of 4 consecutive outputs.
// ---------------------------------------------------------------------------
__global__ __launch_bounds__(256) void pqmf_main(const float* __restrict__ x,
                                                 const float* __restrict__ W,
                                                 const float* __restrict__ H,
                                                 const float* __restrict__ G,
                                                 float* __restrict__ out) {
    int u = blockIdx.x * blockDim.x + threadIdx.x;   // quad index in batch
    int b = blockIdx.y;
    const float* xb = x + (size_t)b * TT;
    float*       ob = out + (size_t)b * TT;

    if (u >= 16 && u <= SS - 17) {
        // ---- fast path: combined 125-tap filter, window fully in bounds ----
        float a0 = 0.f, a1 = 0.f, a2 = 0.f, a3 = 0.f;
        const float4* X4 = reinterpret_cast<const float4*>(xb) + (u - 16);

#define STEP(ii, xs)                                               \
        {                                                          \
            if ((ii) >= 2 && (ii) <= 126) a0 += (xs) * W[0 * WSTRIDE + (ii)]; \
            if ((ii) >= 3 && (ii) <= 127) a1 += (xs) * W[1 * WSTRIDE + (ii)]; \
            if ((ii) >= 4 && (ii) <= 128) a2 += (xs) * W[2 * WSTRIDE + (ii)]; \
            if ((ii) >= 5 && (ii) <= 129) a3 += (xs) * W[3 * WSTRIDE + (ii)]; \
        }

#pragma unroll
        for (int c = 0; c < 33; ++c) {
            float4 v = X4[c];
            STEP(4 * c + 0, v.x)
            STEP(4 * c + 1, v.y)
            STEP(4 * c + 2, v.z)
            STEP(4 * c + 3, v.w)
        }
#undef STEP

        float4 r = make_float4(a0, a1, a2, a3);
        *reinterpret_cast<float4*>(ob + 4 * (size_t)u) = r;
    } else {
        // ---- slow path (edges): explicit two-stage with s/x clamping ----
        int t0 = 4 * u;
        float acc[4] = {0.f, 0.f, 0.f, 0.f};
        int sminq = (t0 - 28) >> 2;            // ceil((t0-31)/4)
        if (sminq < 0) sminq = 0;
        int smaxq = (t0 + 34) >> 2;            // floor((t0+3+31)/4)
        if (smaxq > SS - 1) smaxq = SS - 1;

        for (int si = 0; si < 18; ++si) {
            int s = sminq + si;
            if (s > smaxq) break;
            // sub[k][s] from zero-padded x
            float s0 = 0.f, s1 = 0.f, s2 = 0.f, s3 = 0.f;
            int xbase = 4 * s - 31;
            for (int a = 0; a < 63; ++a) {
                int xi = xbase + a;
                float xv = (xi >= 0 && xi < TT) ? xb[xi] : 0.f;
                s0 += xv * H[0 * 63 + a];
                s1 += xv * H[1 * 63 + a];
                s2 += xv * H[2 * 63 + a];
                s3 += xv * H[3 * 63 + a];
            }
#pragma unroll
            for (int p = 0; p < 4; ++p) {
                int j = 4 * s + 31 - (t0 + p);
                if (j >= 0 && j <= 62) {
                    acc[p] += s0 * G[0 * 63 + j] + s1 * G[1 * 63 + j] +
                              s2 * G[2 * 63 + j] + s3 * G[3 * 63 + j];
                }
            }
        }
#pragma unroll
        for (int p = 0; p < 4; ++p) ob[t0 + p] = 4.f * acc[p];
    }
}

extern "C" void kernel_launch(void* const* d_in, const int* in_sizes, int n_in,
                              void* d_out, int out_size, void* d_ws, size_t ws_size,
                              hipStream_t stream) {
    const float* x = (const float*)d_in[0];
    const float* H = (const float*)d_in[1];
    const float* G = (const float*)d_in[2];
    float* outp = (float*)d_out;
    float* W = (float*)d_ws;   // 4*132 floats = 2112 B

    hipLaunchKernelGGL(build_w, dim3(3), dim3(256), 0, stream, H, G, W);
    hipLaunchKernelGGL(pqmf_main, dim3(SS / 256, BB), dim3(256), 0, stream,
                       x, W, H, G, outp);
}